// Round 5
// baseline (505.027 us; speedup 1.0000x reference)
//
#include <hip/hip_runtime.h>
#include <cstdint>
#include <cstddef>

typedef unsigned short u16;
typedef unsigned int   u32;
typedef __attribute__((ext_vector_type(8))) short bf16x8;
typedef __attribute__((ext_vector_type(4))) float f32x4;

#define MFMA16(a,b,c) __builtin_amdgcn_mfma_f32_16x16x32_bf16((a),(b),(c),0,0,0)

__device__ __forceinline__ float bf2f(u16 h){
  union { u32 u; float f; } v; v.u = ((u32)h) << 16; return v.f;
}
__device__ __forceinline__ u16 f2bf(float f){
  union { float f; u32 u; } v; v.f = f;
  u32 u = v.u + 0x7FFFu + ((v.u >> 16) & 1u);
  return (u16)(u >> 16);
}
__device__ __forceinline__ float ldf(const void* p, int i, u32 isf32){
  return isf32 ? ((const float*)p)[i] : bf2f(((const u16*)p)[i]);
}
// inline dtype probe: raw f32 data seen as bf16 has huge low-half values
__device__ __forceinline__ u32 detectf32(const void* p){
  const float v = bf2f(((const u16*)p)[threadIdx.x & 63]);
  return (__ballot(fabsf(v) > 1.0e6f) != 0ull) ? 1u : 0u;
}
// async global->LDS, 16B/lane; LDS base wave-uniform, lane i lands at base+16i
__device__ __forceinline__ void gload_lds16(const u16* g, u16* lbase){
  auto gp = (const __attribute__((address_space(1))) u32*)(uintptr_t)g;
  auto lp = (__attribute__((address_space(3))) u32*)(uintptr_t)lbase;
  __builtin_amdgcn_global_load_lds(gp, lp, 16, 0, 0);
}
__device__ __forceinline__ void conv8(const void* src, u16* dst, int i8, u32 f){
  if (f) {
    const float4 a = ((const float4*)src)[i8 >> 2];
    const float4 b = ((const float4*)src)[(i8 >> 2) + 1];
    u16 o[8] = { f2bf(a.x), f2bf(a.y), f2bf(a.z), f2bf(a.w),
                 f2bf(b.x), f2bf(b.y), f2bf(b.z), f2bf(b.w) };
    *(uint4*)&dst[i8] = *(const uint4*)o;
  } else {
    ((uint4*)dst)[i8 >> 3] = ((const uint4*)src)[i8 >> 3];
  }
}

// ---------------------------------------------------------------------------
// kPrep: fused conversion/param staging. Region by blockIdx:
// [0,4096)     Cin  = bf16(inputs)           [4096,5120) Cop = bf16(op_emb)
// [5120,6144)  Wcat rows (o=bid-5120)        [6144,6278) PB params
// [6278,6310)  Srw zero
// PB (u16): [0,16384) dgf_opW | [16384,32768) gat_opW | [32768,33024) dgf_b
// [33024,33280) dgf_opb | [33280,33536) gat_opb | [33536,33792) ln_g
// [33792,34048) ln_b
// ---------------------------------------------------------------------------
__global__ void kPrep(const void* inputs, const void* op_emb,
                      const void* dgfW, const void* Wk, const void* Wv,
                      const void* Wq, const void* aw,
                      const void* dgf_opW, const void* gat_opW,
                      const void* dgf_b, const void* dgf_opb,
                      const void* gat_opb, const void* ln_g, const void* ln_b,
                      u16* __restrict__ Cin, u16* __restrict__ Cop,
                      u16* __restrict__ Wcat, u16* __restrict__ PB,
                      float* __restrict__ Srw)
{
  const u32 f = detectf32(inputs);
  const int bid = blockIdx.x, tid = threadIdx.x;
  if (bid < 4096) {
    conv8(inputs, Cin, ((bid << 8) + tid) << 3, f);
  } else if (bid < 5120) {
    conv8(op_emb, Cop, (((bid - 4096) << 8) + tid) << 3, f);
  } else if (bid < 6144) {
    const int o = bid - 5120, i = tid;
    float v;
    if (o < 256)       v = ldf(dgfW, i * 256 + o, f);
    else if (o < 512)  v = ldf(Wk, (o - 256) * 256 + i, f);
    else if (o < 768)  v = ldf(Wv, (o - 512) * 256 + i, f);
    else               v = ldf(Wq, (o - 768) * 256 + i, f) * ldf(aw, o - 768, f) * 0.0625f;
    Wcat[o * 256 + i] = f2bf(v);
  } else if (bid < 6278) {
    const int i = ((bid - 6144) << 8) + tid;
    if (i < 34048) {
      float v;
      if      (i < 16384) v = ldf(dgf_opW, i, f);
      else if (i < 32768) v = ldf(gat_opW, i - 16384, f);
      else if (i < 33024) v = ldf(dgf_b,   i - 32768, f);
      else if (i < 33280) v = ldf(dgf_opb, i - 33024, f);
      else if (i < 33536) v = ldf(gat_opb, i - 33280, f);
      else if (i < 33792) v = ldf(ln_g,    i - 33536, f);
      else                v = ldf(ln_b,    i - 33792, f);
      PB[i] = f2bf(v);
    }
  } else {
    ((float4*)Srw)[((bid - 6278) << 8) + tid] = float4{0.f, 0.f, 0.f, 0.f};
  }
}

// ---------------------------------------------------------------------------
// K1: X[32768,256] @ WcatT^T, 128x128 tiles, BK=64, async staging, XOR swizzle.
// ct 0-3: support/Whk -> P ; 6,7: Whq_pre -> P
// ct 4,5: Whv -> T rows 256-511 (swapped => C^T) ; 8,9: support -> T rows 0-255
// P [32768,768]: 0-255 support, 256-511 Whk, 512-767 Whq_pre.
// T [64][512][512]: rows 0-255 supportT, 256-511 WhvT.
// ---------------------------------------------------------------------------
__global__ __launch_bounds__(256, 4)
void k1_proj(const u16* __restrict__ X, const u16* __restrict__ W,
             u16* __restrict__ P, u16* __restrict__ T)
{
  __shared__ __align__(16) u16 ldsA[128 * 64];
  __shared__ __align__(16) u16 ldsB[128 * 64];
  const int bt = blockIdx.x;
  const int ct = blockIdx.y;
  const int r0 = bt << 7;
  const bool swapped = (ct == 4) | (ct == 5) | (ct >= 8);
  const int wbase = (ct < 8) ? (ct << 7) : ((ct - 8) << 7);
  const int tid = threadIdx.x;
  const int wave = tid >> 6;
  const int lane = tid & 63;
  const int wm = wave >> 1, wn = wave & 1;

  f32x4 acc[4][4];
#pragma unroll
  for (int i = 0; i < 4; ++i)
#pragma unroll
    for (int j = 0; j < 4; ++j) acc[i][j] = f32x4{0.f, 0.f, 0.f, 0.f};

  for (int kt = 0; kt < 4; ++kt) {
    __syncthreads();
#pragma unroll
    for (int s = 0; s < 4; ++s) {
      const int bslot = (wave * 4 + s) << 6;   // wave-uniform LDS base
      const int slot = bslot + lane;
      const int m = slot >> 3, c = slot & 7;
      const int kb = c ^ (m & 7);
      gload_lds16(X + (r0 + m) * 256 + (kt << 6) + (kb << 3), &ldsA[bslot << 3]);
      gload_lds16(W + (wbase + m) * 256 + (kt << 6) + (kb << 3), &ldsB[bslot << 3]);
    }
    __syncthreads();
#pragma unroll
    for (int ks = 0; ks < 2; ++ks) {
      const int kb = (ks << 2) + (lane >> 4);
      bf16x8 fa[4], fb[4];
#pragma unroll
      for (int i = 0; i < 4; ++i) {
        const int m = (wm << 6) + (i << 4) + (lane & 15);
        fa[i] = *(const bf16x8*)&ldsA[((m << 3) + (kb ^ (m & 7))) << 3];
        const int n = (wn << 6) + (i << 4) + (lane & 15);
        fb[i] = *(const bf16x8*)&ldsB[((n << 3) + (kb ^ (n & 7))) << 3];
      }
      if (!swapped) {
#pragma unroll
        for (int i = 0; i < 4; ++i)
#pragma unroll
          for (int j = 0; j < 4; ++j)
            acc[i][j] = MFMA16(fa[i], fb[j], acc[i][j]);
      } else {
#pragma unroll
        for (int i = 0; i < 4; ++i)
#pragma unroll
          for (int j = 0; j < 4; ++j)
            acc[i][j] = MFMA16(fb[i], fa[j], acc[i][j]);
      }
    }
  }

  if (!swapped) {
    const int pcb = (ct < 4) ? (ct << 7) : ((ct - 2) << 7);
#pragma unroll
    for (int i = 0; i < 4; ++i) {
      const int row = r0 + (wm << 6) + (i << 4) + ((lane >> 4) << 2);
#pragma unroll
      for (int j = 0; j < 4; ++j) {
        const int col = pcb + (wn << 6) + (j << 4) + (lane & 15);
#pragma unroll
        for (int r = 0; r < 4; ++r)
          P[(row + r) * 768 + col] = f2bf(acc[i][j][r]);
      }
    }
  } else {
    // swapped: C rows carry wn offset, C cols carry wm offset
    const int trb = (wbase >= 512) ? (wbase - 256) : wbase;
    const int b = r0 >> 9;
    const int e0 = r0 & 511;
    u16* Tb = T + ((size_t)b << 18);
#pragma unroll
    for (int i = 0; i < 4; ++i) {
      const int trow = trb + (wn << 6) + (i << 4) + ((lane >> 4) << 2);
#pragma unroll
      for (int j = 0; j < 4; ++j) {
        const int e = e0 + (wm << 6) + (j << 4) + (lane & 15);
#pragma unroll
        for (int r = 0; r < 4; ++r)
          Tb[((trow + r) << 9) + e] = f2bf(acc[i][j][r]);
      }
    }
  }
}

// ---------------------------------------------------------------------------
// K2: G[32768,512] = sigmoid(op_emb @ opW^T + b); cols 0-255 gate_d, 256-511 gate_g
// ---------------------------------------------------------------------------
__global__ __launch_bounds__(256, 4)
void k2_gates(const u16* __restrict__ OP, const u16* __restrict__ PB,
              u16* __restrict__ G)
{
  __shared__ __align__(16) u16 ldsA[128 * 64];
  __shared__ __align__(16) u16 ldsB[128 * 64];
  const int bt = blockIdx.x, ct = blockIdx.y;
  const int r0 = bt << 7;
  const u16* Wp = (ct < 2) ? (PB + (ct << 7) * 64) : (PB + 16384 + ((ct - 2) << 7) * 64);
  const u16* Bp = (ct < 2) ? (PB + 33024 + (ct << 7)) : (PB + 33280 + ((ct - 2) << 7));
  const int tid = threadIdx.x, wave = tid >> 6, lane = tid & 63;
  const int wm = wave >> 1, wn = wave & 1;

  f32x4 acc[4][4];
#pragma unroll
  for (int i = 0; i < 4; ++i)
#pragma unroll
    for (int j = 0; j < 4; ++j) acc[i][j] = f32x4{0.f, 0.f, 0.f, 0.f};

#pragma unroll
  for (int s = 0; s < 4; ++s) {
    const int bslot = (wave * 4 + s) << 6;
    const int slot = bslot + lane;
    const int m = slot >> 3, c = slot & 7;
    const int kb = c ^ (m & 7);
    gload_lds16(OP + (r0 + m) * 64 + (kb << 3), &ldsA[bslot << 3]);
    gload_lds16(Wp + m * 64 + (kb << 3), &ldsB[bslot << 3]);
  }
  __syncthreads();
#pragma unroll
  for (int ks = 0; ks < 2; ++ks) {
    const int kb = (ks << 2) + (lane >> 4);
    bf16x8 fa[4], fb[4];
#pragma unroll
    for (int i = 0; i < 4; ++i) {
      const int m = (wm << 6) + (i << 4) + (lane & 15);
      fa[i] = *(const bf16x8*)&ldsA[((m << 3) + (kb ^ (m & 7))) << 3];
      const int n = (wn << 6) + (i << 4) + (lane & 15);
      fb[i] = *(const bf16x8*)&ldsB[((n << 3) + (kb ^ (n & 7))) << 3];
    }
#pragma unroll
    for (int i = 0; i < 4; ++i)
#pragma unroll
      for (int j = 0; j < 4; ++j)
        acc[i][j] = MFMA16(fa[i], fb[j], acc[i][j]);
  }
#pragma unroll
  for (int i = 0; i < 4; ++i) {
    const int row = r0 + (wm << 6) + (i << 4) + ((lane >> 4) << 2);
#pragma unroll
    for (int j = 0; j < 4; ++j) {
      const int cw = (wn << 6) + (j << 4) + (lane & 15);
      const float bias = bf2f(Bp[cw]);
      const int col = (ct << 7) + cw;
#pragma unroll
      for (int r = 0; r < 4; ++r) {
        const float x = acc[i][j][r] + bias;
        G[((row + r) << 9) + col] = f2bf(1.0f / (1.0f + __expf(-x)));
      }
    }
  }
}

// ---------------------------------------------------------------------------
// K3: scores S = Whq_pre @ Whk^T. Epilogue: reads RAW adj (dtype branch),
// writes E = exp(leaky(S)*adj) bf16, Cadj = bf16(adj), and atomicAdds the
// softmax row sums into Srw (zeroed by kPrep). No max-subtraction needed.
// ---------------------------------------------------------------------------
__global__ __launch_bounds__(256, 4)
void k3_scores(const u16* __restrict__ P, const void* __restrict__ adjR,
               u16* __restrict__ E, u16* __restrict__ Cadj,
               float* __restrict__ Srw)
{
  __shared__ __align__(16) u16 ldsA[128 * 64];
  __shared__ __align__(16) u16 ldsB[128 * 64];
  const int lt = blockIdx.x, et = blockIdx.y, b = blockIdx.z;
  const int e0 = et << 7, l0 = lt << 7;
  const int tid = threadIdx.x, wave = tid >> 6, lane = tid & 63;
  const int wm = wave >> 1, wn = wave & 1;
  const int rowQ = (b << 9) + e0;
  const int rowK = (b << 9) + l0;
  const u32 isf32 = detectf32(adjR);

  f32x4 acc[4][4];
#pragma unroll
  for (int i = 0; i < 4; ++i)
#pragma unroll
    for (int j = 0; j < 4; ++j) acc[i][j] = f32x4{0.f, 0.f, 0.f, 0.f};

  for (int kt = 0; kt < 4; ++kt) {
    __syncthreads();
#pragma unroll
    for (int s = 0; s < 4; ++s) {
      const int bslot = (wave * 4 + s) << 6;
      const int slot = bslot + lane;
      const int m = slot >> 3, c = slot & 7;
      const int kb = c ^ (m & 7);
      gload_lds16(P + (rowQ + m) * 768 + 512 + (kt << 6) + (kb << 3), &ldsA[bslot << 3]);
      gload_lds16(P + (rowK + m) * 768 + 256 + (kt << 6) + (kb << 3), &ldsB[bslot << 3]);
    }
    __syncthreads();
#pragma unroll
    for (int ks = 0; ks < 2; ++ks) {
      const int kb = (ks << 2) + (lane >> 4);
      bf16x8 fa[4], fb[4];
#pragma unroll
      for (int i = 0; i < 4; ++i) {
        const int m = (wm << 6) + (i << 4) + (lane & 15);
        fa[i] = *(const bf16x8*)&ldsA[((m << 3) + (kb ^ (m & 7))) << 3];
        const int n = (wn << 6) + (i << 4) + (lane & 15);
        fb[i] = *(const bf16x8*)&ldsB[((n << 3) + (kb ^ (n & 7))) << 3];
      }
#pragma unroll
      for (int i = 0; i < 4; ++i)
#pragma unroll
        for (int j = 0; j < 4; ++j)
          acc[i][j] = MFMA16(fa[i], fb[j], acc[i][j]);
    }
  }
#pragma unroll
  for (int i = 0; i < 4; ++i) {
#pragma unroll
    for (int r = 0; r < 4; ++r) {
      const int e = e0 + (wm << 6) + (i << 4) + ((lane >> 4) << 2) + r;
      const int grow = (b << 9) + e;
      float part = 0.0f;
#pragma unroll
      for (int j = 0; j < 4; ++j) {
        const int l = l0 + (wn << 6) + (j << 4) + (lane & 15);
        const int idx = (grow << 9) + l;
        const float a = isf32 ? ((const float*)adjR)[idx]
                              : bf2f(((const u16*)adjR)[idx]);
        float s = acc[i][j][r];
        s = (s > 0.0f ? s : 0.2f * s) * a;
        const float ex = __expf(s);
        E[idx] = f2bf(ex);
        Cadj[idx] = f2bf(a);
        part += ex;
      }
#pragma unroll
      for (int m = 1; m < 16; m <<= 1) part += __shfl_xor(part, m, 64);
      if ((lane & 15) == 0) atomicAdd(&Srw[grow], part);
    }
  }
}

// ---------------------------------------------------------------------------
// K4: per (b, 32-row e-tile): phase0 H = E @ Whv (via WhvT); phase1
// D = adj @ support (via supportT). Epilogue: h'=gate_g*H/S; LayerNorm;
// dense=gate_d*D+support+dgf_b; out=0.5*(dense+gat), dtype-branched store.
// ---------------------------------------------------------------------------
__global__ __launch_bounds__(256, 4)
void k4_out(const u16* __restrict__ P, const u16* __restrict__ T,
            const u16* __restrict__ E, const u16* __restrict__ Cadj,
            const float* __restrict__ S, const u16* __restrict__ G,
            const u16* __restrict__ PB, void* __restrict__ out,
            const void* __restrict__ rawIn)
{
  __shared__ __align__(16) u16 ldsA[32 * 64];    // 4 KB
  __shared__ __align__(16) u16 ldsB[256 * 64];   // 32 KB
  __shared__ float red[32][4];
  const int et = blockIdx.x, b = blockIdx.y;
  const int e0 = et << 5;
  const int tid = threadIdx.x, wave = tid >> 6, lane = tid & 63;
  const int wm = wave >> 1, wn = wave & 1;
  const size_t abase = ((size_t)((b << 9) + e0)) << 9;
  const u16* Ea  = E + abase;
  const u16* Aa  = Cadj + abase;
  const u16* Tb  = T + ((size_t)b << 18);
  const u16* WhvT = Tb + (256 << 9);
  const u16* SupT = Tb;
  const u16* dgf_b = PB + 32768;
  const u16* ln_g  = PB + 33536;
  const u16* ln_b  = PB + 33792;
  const u32 isf32 = detectf32(rawIn);

  f32x4 acc[2][8];
#pragma unroll
  for (int p = 0; p < 2; ++p)
#pragma unroll
    for (int j = 0; j < 8; ++j) acc[p][j] = f32x4{0.f, 0.f, 0.f, 0.f};

#pragma unroll
  for (int ph = 0; ph < 2; ++ph) {
    const u16* Ag = ph ? Aa : Ea;
    const u16* Bg = ph ? SupT : WhvT;
    for (int lt = 0; lt < 8; ++lt) {
      __syncthreads();
      {
        const int bslot = wave << 6;
        const int slot = bslot + lane;
        const int m = slot >> 3, c = slot & 7;
        const int kb = c ^ (m & 7);
        gload_lds16(Ag + (m << 9) + (lt << 6) + (kb << 3), &ldsA[bslot << 3]);
      }
#pragma unroll
      for (int s2 = 0; s2 < 8; ++s2) {
        const int bslot = (wave * 8 + s2) << 6;
        const int slot = bslot + lane;
        const int m = slot >> 3, c = slot & 7;
        const int kb = c ^ (m & 7);
        gload_lds16(Bg + (m << 9) + (lt << 6) + (kb << 3), &ldsB[bslot << 3]);
      }
      __syncthreads();
#pragma unroll
      for (int ks = 0; ks < 2; ++ks) {
        const int kb = (ks << 2) + (lane >> 4);
        const int m = (wm << 4) + (lane & 15);
        const bf16x8 fa = *(const bf16x8*)&ldsA[((m << 3) + (kb ^ (m & 7))) << 3];
#pragma unroll
        for (int j = 0; j < 8; ++j) {
          const int n = (wn << 7) + (j << 4) + (lane & 15);
          const bf16x8 fb = *(const bf16x8*)&ldsB[((n << 3) + (kb ^ (n & 7))) << 3];
          acc[ph][j] = MFMA16(fa, fb, acc[ph][j]);
        }
      }
    }
  }

  const int cb = wn << 7;
  float lng[8], lnb[8], dgb[8];
#pragma unroll
  for (int j = 0; j < 8; ++j) {
    const int col = cb + (j << 4) + (lane & 15);
    lng[j] = bf2f(ln_g[col]);
    lnb[j] = bf2f(ln_b[col]);
    dgb[j] = bf2f(dgf_b[col]);
  }
#pragma unroll
  for (int r = 0; r < 4; ++r) {
    const int rl = (wm << 4) + ((lane >> 4) << 2) + r;
    const int grow = (b << 9) + e0 + rl;
    const float invS = 1.0f / S[grow];
    float ps = 0.0f, pq = 0.0f;
#pragma unroll
    for (int j = 0; j < 8; ++j) {
      const int col = cb + (j << 4) + (lane & 15);
      const float gg = bf2f(G[((size_t)grow << 9) + 256 + col]);
      const float hp = gg * acc[0][j][r] * invS;
      acc[0][j][r] = hp;
      ps += hp; pq += hp * hp;
    }
#pragma unroll
    for (int m = 1; m < 16; m <<= 1) {
      ps += __shfl_xor(ps, m, 64);
      pq += __shfl_xor(pq, m, 64);
    }
    if ((lane & 15) == 0) { red[rl][wn << 1] = ps; red[rl][(wn << 1) + 1] = pq; }
  }
  __syncthreads();
#pragma unroll
  for (int r = 0; r < 4; ++r) {
    const int rl = (wm << 4) + ((lane >> 4) << 2) + r;
    const int grow = (b << 9) + e0 + rl;
    const float mean = (red[rl][0] + red[rl][2]) * (1.0f / 256.0f);
    const float ex2  = (red[rl][1] + red[rl][3]) * (1.0f / 256.0f);
    const float rstd = rsqrtf(ex2 - mean * mean + 1e-5f);
#pragma unroll
    for (int j = 0; j < 8; ++j) {
      const int col = cb + (j << 4) + (lane & 15);
      const float gat = (acc[0][j][r] - mean) * rstd * lng[j] + lnb[j];
      const float gd = bf2f(G[((size_t)grow << 9) + col]);
      const float sup = bf2f(P[grow * 768 + col]);
      const float dense = gd * acc[1][j][r] + sup + dgb[j];
      const float o = 0.5f * (dense + gat);
      if (isf32) ((float*)out)[grow * 256 + col] = o;
      else       ((u16*)out)[grow * 256 + col] = f2bf(o);
    }
  }
}

// ---------------------------------------------------------------------------
extern "C" void kernel_launch(void* const* d_in, const int* in_sizes, int n_in,
                              void* d_out, int out_size, void* d_ws, size_t ws_size,
                              hipStream_t stream)
{
  (void)in_sizes; (void)n_in; (void)out_size; (void)ws_size;
  const void* inputs  = d_in[0];
  const void* adj     = d_in[1];
  const void* op_emb  = d_in[2];
  const void* dgf_W   = d_in[3];
  const void* dgf_b   = d_in[4];
  const void* dgf_opW = d_in[5];
  const void* dgf_opb = d_in[6];
  const void* Wk      = d_in[7];
  const void* Wv      = d_in[8];
  const void* Wq      = d_in[9];
  const void* a_w     = d_in[10];
  const void* gat_opW = d_in[11];
  const void* gat_opb = d_in[12];
  const void* ln_g    = d_in[13];
  const void* ln_b    = d_in[14];
  char* ws = (char*)d_ws;

  // workspace layout (bytes)
  u16*  P    = (u16*)(ws);                    // [32768,768]  50331648
  u16*  T    = (u16*)(ws + 50331648ull);      // [64,512,512] 33554432
  u16*  E    = (u16*)(ws + 83886080ull);      // [64,512,512] 33554432
  u16*  G    = (u16*)(ws + 117440512ull);     // [32768,512]  33554432
  u16*  Cadj = (u16*)(ws + 150994944ull);     // [64,512,512] 33554432
  u16*  Cin  = (u16*)(ws + 184549376ull);     // [32768,256]  16777216
  u16*  Cop  = (u16*)(ws + 201326592ull);     // [32768,64]    4194304
  u16*  Wcat = (u16*)(ws + 205520896ull);     // [1024,256]     524288
  u16*  PB   = (u16*)(ws + 206045184ull);     // params          69632
  float* Srw = (float*)(ws + 206114816ull);   // [32768] f32    131072

  kPrep    <<<dim3(6310),     dim3(256), 0, stream>>>(inputs, op_emb,
                dgf_W, Wk, Wv, Wq, a_w, dgf_opW, gat_opW, dgf_b, dgf_opb,
                gat_opb, ln_g, ln_b, Cin, Cop, Wcat, PB, Srw);
  k1_proj  <<<dim3(256, 10),  dim3(256), 0, stream>>>(Cin, Wcat, P, T);
  k2_gates <<<dim3(256, 4),   dim3(256), 0, stream>>>(Cop, PB, G);
  k3_scores<<<dim3(4, 4, 64), dim3(256), 0, stream>>>(P, adj, E, Cadj, Srw);
  k4_out   <<<dim3(16, 64),   dim3(256), 0, stream>>>(P, T, E, Cadj, Srw, G,
                                                      PB, d_out, inputs);
}

// Round 6
// 416.334 us; speedup vs baseline: 1.2130x; 1.2130x over previous
//
#include <hip/hip_runtime.h>
#include <cstdint>
#include <cstddef>

typedef unsigned short u16;
typedef unsigned int   u32;
typedef __attribute__((ext_vector_type(8))) short bf16x8;
typedef __attribute__((ext_vector_type(4))) float f32x4;

#define MFMA16(a,b,c) __builtin_amdgcn_mfma_f32_16x16x32_bf16((a),(b),(c),0,0,0)

__device__ __forceinline__ float bf2f(u16 h){
  union { u32 u; float f; } v; v.u = ((u32)h) << 16; return v.f;
}
__device__ __forceinline__ u16 f2bf(float f){
  union { float f; u32 u; } v; v.f = f;
  u32 u = v.u + 0x7FFFu + ((v.u >> 16) & 1u);
  return (u16)(u >> 16);
}
__device__ __forceinline__ float ldf(const void* p, int i, u32 isf32){
  return isf32 ? ((const float*)p)[i] : bf2f(((const u16*)p)[i]);
}
// inline dtype probe: raw f32 data seen as bf16 has huge low-half values
__device__ __forceinline__ u32 detectf32(const void* p){
  const float v = bf2f(((const u16*)p)[threadIdx.x & 63]);
  return (__ballot(fabsf(v) > 1.0e6f) != 0ull) ? 1u : 0u;
}
__device__ __forceinline__ void conv8(const void* src, u16* dst, int i8, u32 f){
  if (f) {
    const float4 a = ((const float4*)src)[i8 >> 2];
    const float4 b = ((const float4*)src)[(i8 >> 2) + 1];
    u16 o[8] = { f2bf(a.x), f2bf(a.y), f2bf(a.z), f2bf(a.w),
                 f2bf(b.x), f2bf(b.y), f2bf(b.z), f2bf(b.w) };
    *(uint4*)&dst[i8] = *(const uint4*)o;
  } else {
    ((uint4*)dst)[i8 >> 3] = ((const uint4*)src)[i8 >> 3];
  }
}

// ---------------------------------------------------------------------------
// kPrep: fused conversion/param staging. Region by blockIdx:
// [0,4096) Cin | [4096,5120) Cop | [5120,6144) Wcat | [6144,6278) PB
// [6278,6310) Srw zero
// PB (u16): [0,16384) dgf_opW | [16384,32768) gat_opW | [32768,33024) dgf_b
// [33024,33280) dgf_opb | [33280,33536) gat_opb | [33536,33792) ln_g
// [33792,34048) ln_b
// ---------------------------------------------------------------------------
__global__ void kPrep(const void* inputs, const void* op_emb,
                      const void* dgfW, const void* Wk, const void* Wv,
                      const void* Wq, const void* aw,
                      const void* dgf_opW, const void* gat_opW,
                      const void* dgf_b, const void* dgf_opb,
                      const void* gat_opb, const void* ln_g, const void* ln_b,
                      u16* __restrict__ Cin, u16* __restrict__ Cop,
                      u16* __restrict__ Wcat, u16* __restrict__ PB,
                      float* __restrict__ Srw)
{
  const u32 f = detectf32(inputs);
  const int bid = blockIdx.x, tid = threadIdx.x;
  if (bid < 4096) {
    conv8(inputs, Cin, ((bid << 8) + tid) << 3, f);
  } else if (bid < 5120) {
    conv8(op_emb, Cop, (((bid - 4096) << 8) + tid) << 3, f);
  } else if (bid < 6144) {
    const int o = bid - 5120, i = tid;
    float v;
    if (o < 256)       v = ldf(dgfW, i * 256 + o, f);
    else if (o < 512)  v = ldf(Wk, (o - 256) * 256 + i, f);
    else if (o < 768)  v = ldf(Wv, (o - 512) * 256 + i, f);
    else               v = ldf(Wq, (o - 768) * 256 + i, f) * ldf(aw, o - 768, f) * 0.0625f;
    Wcat[o * 256 + i] = f2bf(v);
  } else if (bid < 6278) {
    const int i = ((bid - 6144) << 8) + tid;
    if (i < 34048) {
      float v;
      if      (i < 16384) v = ldf(dgf_opW, i, f);
      else if (i < 32768) v = ldf(gat_opW, i - 16384, f);
      else if (i < 33024) v = ldf(dgf_b,   i - 32768, f);
      else if (i < 33280) v = ldf(dgf_opb, i - 33024, f);
      else if (i < 33536) v = ldf(gat_opb, i - 33280, f);
      else if (i < 33792) v = ldf(ln_g,    i - 33536, f);
      else                v = ldf(ln_b,    i - 33792, f);
      PB[i] = f2bf(v);
    }
  } else {
    ((float4*)Srw)[((bid - 6278) << 8) + tid] = float4{0.f, 0.f, 0.f, 0.f};
  }
}

// ---------------------------------------------------------------------------
// K1: X[32768,256] @ WcatT^T, 128x128 tiles, BK=64, explicit uint4 staging
// (R4-proven config), XOR-swizzled LDS.
// ct 0-3: support/Whk -> P ; 6,7: Whq_pre -> P
// ct 4,5: Whv -> T rows 256-511 (swapped => C^T) ; 8,9: support -> T rows 0-255
// ---------------------------------------------------------------------------
__global__ __launch_bounds__(256, 2)
void k1_proj(const u16* __restrict__ X, const u16* __restrict__ W,
             u16* __restrict__ P, u16* __restrict__ T)
{
  __shared__ __align__(16) u16 ldsA[128 * 64];
  __shared__ __align__(16) u16 ldsB[128 * 64];
  const int bt = blockIdx.x;
  const int ct = blockIdx.y;
  const int r0 = bt << 7;
  const bool swapped = (ct == 4) | (ct == 5) | (ct >= 8);
  const int wbase = (ct < 8) ? (ct << 7) : ((ct - 8) << 7);
  const int tid = threadIdx.x;
  const int wave = tid >> 6;
  const int lane = tid & 63;
  const int wm = wave >> 1, wn = wave & 1;

  f32x4 acc[4][4];
#pragma unroll
  for (int i = 0; i < 4; ++i)
#pragma unroll
    for (int j = 0; j < 4; ++j) acc[i][j] = f32x4{0.f, 0.f, 0.f, 0.f};

  for (int kt = 0; kt < 4; ++kt) {
    __syncthreads();
#pragma unroll
    for (int s = 0; s < 4; ++s) {
      const int slot = ((wave * 4 + s) << 6) + lane;
      const int m = slot >> 3, c = slot & 7;
      const int kb = c ^ (m & 7);
      *(uint4*)&ldsA[slot << 3] =
          *(const uint4*)(X + (r0 + m) * 256 + (kt << 6) + (kb << 3));
      *(uint4*)&ldsB[slot << 3] =
          *(const uint4*)(W + (wbase + m) * 256 + (kt << 6) + (kb << 3));
    }
    __syncthreads();
#pragma unroll
    for (int ks = 0; ks < 2; ++ks) {
      const int kb = (ks << 2) + (lane >> 4);
      bf16x8 fa[4], fb[4];
#pragma unroll
      for (int i = 0; i < 4; ++i) {
        const int m = (wm << 6) + (i << 4) + (lane & 15);
        fa[i] = *(const bf16x8*)&ldsA[((m << 3) + (kb ^ (m & 7))) << 3];
        const int n = (wn << 6) + (i << 4) + (lane & 15);
        fb[i] = *(const bf16x8*)&ldsB[((n << 3) + (kb ^ (n & 7))) << 3];
      }
      if (!swapped) {
#pragma unroll
        for (int i = 0; i < 4; ++i)
#pragma unroll
          for (int j = 0; j < 4; ++j)
            acc[i][j] = MFMA16(fa[i], fb[j], acc[i][j]);
      } else {
#pragma unroll
        for (int i = 0; i < 4; ++i)
#pragma unroll
          for (int j = 0; j < 4; ++j)
            acc[i][j] = MFMA16(fb[i], fa[j], acc[i][j]);
      }
    }
  }

  if (!swapped) {
    const int pcb = (ct < 4) ? (ct << 7) : ((ct - 2) << 7);
#pragma unroll
    for (int i = 0; i < 4; ++i) {
      const int row = r0 + (wm << 6) + (i << 4) + ((lane >> 4) << 2);
#pragma unroll
      for (int j = 0; j < 4; ++j) {
        const int col = pcb + (wn << 6) + (j << 4) + (lane & 15);
#pragma unroll
        for (int r = 0; r < 4; ++r)
          P[(row + r) * 768 + col] = f2bf(acc[i][j][r]);
      }
    }
  } else {
    // swapped: C rows carry wn offset, C cols carry wm offset
    const int trb = (wbase >= 512) ? (wbase - 256) : wbase;
    const int b = r0 >> 9;
    const int e0 = r0 & 511;
    u16* Tb = T + ((size_t)b << 18);
#pragma unroll
    for (int i = 0; i < 4; ++i) {
      const int trow = trb + (wn << 6) + (i << 4) + ((lane >> 4) << 2);
#pragma unroll
      for (int j = 0; j < 4; ++j) {
        const int e = e0 + (wm << 6) + (j << 4) + (lane & 15);
#pragma unroll
        for (int r = 0; r < 4; ++r)
          Tb[((trow + r) << 9) + e] = f2bf(acc[i][j][r]);
      }
    }
  }
}

// ---------------------------------------------------------------------------
// K2: G[32768,512] = sigmoid(op_emb @ opW^T + b); cols 0-255 gate_d, 256-511 gate_g
// ---------------------------------------------------------------------------
__global__ __launch_bounds__(256, 2)
void k2_gates(const u16* __restrict__ OP, const u16* __restrict__ PB,
              u16* __restrict__ G)
{
  __shared__ __align__(16) u16 ldsA[128 * 64];
  __shared__ __align__(16) u16 ldsB[128 * 64];
  const int bt = blockIdx.x, ct = blockIdx.y;
  const int r0 = bt << 7;
  const u16* Wp = (ct < 2) ? (PB + (ct << 7) * 64) : (PB + 16384 + ((ct - 2) << 7) * 64);
  const u16* Bp = (ct < 2) ? (PB + 33024 + (ct << 7)) : (PB + 33280 + ((ct - 2) << 7));
  const int tid = threadIdx.x, wave = tid >> 6, lane = tid & 63;
  const int wm = wave >> 1, wn = wave & 1;

  f32x4 acc[4][4];
#pragma unroll
  for (int i = 0; i < 4; ++i)
#pragma unroll
    for (int j = 0; j < 4; ++j) acc[i][j] = f32x4{0.f, 0.f, 0.f, 0.f};

#pragma unroll
  for (int s = 0; s < 4; ++s) {
    const int slot = ((wave * 4 + s) << 6) + lane;
    const int m = slot >> 3, c = slot & 7;
    const int kb = c ^ (m & 7);
    *(uint4*)&ldsA[slot << 3] = *(const uint4*)(OP + (r0 + m) * 64 + (kb << 3));
    *(uint4*)&ldsB[slot << 3] = *(const uint4*)(Wp + m * 64 + (kb << 3));
  }
  __syncthreads();
#pragma unroll
  for (int ks = 0; ks < 2; ++ks) {
    const int kb = (ks << 2) + (lane >> 4);
    bf16x8 fa[4], fb[4];
#pragma unroll
    for (int i = 0; i < 4; ++i) {
      const int m = (wm << 6) + (i << 4) + (lane & 15);
      fa[i] = *(const bf16x8*)&ldsA[((m << 3) + (kb ^ (m & 7))) << 3];
      const int n = (wn << 6) + (i << 4) + (lane & 15);
      fb[i] = *(const bf16x8*)&ldsB[((n << 3) + (kb ^ (n & 7))) << 3];
    }
#pragma unroll
    for (int i = 0; i < 4; ++i)
#pragma unroll
      for (int j = 0; j < 4; ++j)
        acc[i][j] = MFMA16(fa[i], fb[j], acc[i][j]);
  }
#pragma unroll
  for (int i = 0; i < 4; ++i) {
    const int row = r0 + (wm << 6) + (i << 4) + ((lane >> 4) << 2);
#pragma unroll
    for (int j = 0; j < 4; ++j) {
      const int cw = (wn << 6) + (j << 4) + (lane & 15);
      const float bias = bf2f(Bp[cw]);
      const int col = (ct << 7) + cw;
#pragma unroll
      for (int r = 0; r < 4; ++r) {
        const float x = acc[i][j][r] + bias;
        G[((row + r) << 9) + col] = f2bf(1.0f / (1.0f + __expf(-x)));
      }
    }
  }
}

// ---------------------------------------------------------------------------
// K3: scores S = Whq_pre @ Whk^T. Epilogue: reads RAW adj (dtype branch),
// writes E = exp(leaky(S)*adj) bf16, Cadj = bf16(adj), atomicAdds row sums
// into Srw (zeroed by kPrep). No max-subtraction needed (|alpha| < ~0.2).
// ---------------------------------------------------------------------------
__global__ __launch_bounds__(256, 2)
void k3_scores(const u16* __restrict__ P, const void* __restrict__ adjR,
               u16* __restrict__ E, u16* __restrict__ Cadj,
               float* __restrict__ Srw)
{
  __shared__ __align__(16) u16 ldsA[128 * 64];
  __shared__ __align__(16) u16 ldsB[128 * 64];
  const int lt = blockIdx.x, et = blockIdx.y, b = blockIdx.z;
  const int e0 = et << 7, l0 = lt << 7;
  const int tid = threadIdx.x, wave = tid >> 6, lane = tid & 63;
  const int wm = wave >> 1, wn = wave & 1;
  const int rowQ = (b << 9) + e0;
  const int rowK = (b << 9) + l0;
  const u32 isf32 = detectf32(adjR);

  f32x4 acc[4][4];
#pragma unroll
  for (int i = 0; i < 4; ++i)
#pragma unroll
    for (int j = 0; j < 4; ++j) acc[i][j] = f32x4{0.f, 0.f, 0.f, 0.f};

  for (int kt = 0; kt < 4; ++kt) {
    __syncthreads();
#pragma unroll
    for (int s = 0; s < 4; ++s) {
      const int slot = ((wave * 4 + s) << 6) + lane;
      const int m = slot >> 3, c = slot & 7;
      const int kb = c ^ (m & 7);
      *(uint4*)&ldsA[slot << 3] =
          *(const uint4*)(P + (rowQ + m) * 768 + 512 + (kt << 6) + (kb << 3));
      *(uint4*)&ldsB[slot << 3] =
          *(const uint4*)(P + (rowK + m) * 768 + 256 + (kt << 6) + (kb << 3));
    }
    __syncthreads();
#pragma unroll
    for (int ks = 0; ks < 2; ++ks) {
      const int kb = (ks << 2) + (lane >> 4);
      bf16x8 fa[4], fb[4];
#pragma unroll
      for (int i = 0; i < 4; ++i) {
        const int m = (wm << 6) + (i << 4) + (lane & 15);
        fa[i] = *(const bf16x8*)&ldsA[((m << 3) + (kb ^ (m & 7))) << 3];
        const int n = (wn << 6) + (i << 4) + (lane & 15);
        fb[i] = *(const bf16x8*)&ldsB[((n << 3) + (kb ^ (n & 7))) << 3];
      }
#pragma unroll
      for (int i = 0; i < 4; ++i)
#pragma unroll
        for (int j = 0; j < 4; ++j)
          acc[i][j] = MFMA16(fa[i], fb[j], acc[i][j]);
    }
  }
#pragma unroll
  for (int i = 0; i < 4; ++i) {
#pragma unroll
    for (int r = 0; r < 4; ++r) {
      const int e = e0 + (wm << 6) + (i << 4) + ((lane >> 4) << 2) + r;
      const int grow = (b << 9) + e;
      float part = 0.0f;
#pragma unroll
      for (int j = 0; j < 4; ++j) {
        const int l = l0 + (wn << 6) + (j << 4) + (lane & 15);
        const int idx = (grow << 9) + l;
        const float a = isf32 ? ((const float*)adjR)[idx]
                              : bf2f(((const u16*)adjR)[idx]);
        float s = acc[i][j][r];
        s = (s > 0.0f ? s : 0.2f * s) * a;
        const float ex = __expf(s);
        E[idx] = f2bf(ex);
        Cadj[idx] = f2bf(a);
        part += ex;
      }
#pragma unroll
      for (int m = 1; m < 16; m <<= 1) part += __shfl_xor(part, m, 64);
      if ((lane & 15) == 0) atomicAdd(&Srw[grow], part);
    }
  }
}

// ---------------------------------------------------------------------------
// K4: per (b, 32-row e-tile): phase0 H = E @ Whv (via WhvT); phase1
// D = adj @ support (via supportT). Epilogue: h'=gate_g*H/S; LayerNorm;
// dense=gate_d*D+support+dgf_b; out=0.5*(dense+gat), dtype-branched store.
// ---------------------------------------------------------------------------
__global__ __launch_bounds__(256, 2)
void k4_out(const u16* __restrict__ P, const u16* __restrict__ T,
            const u16* __restrict__ E, const u16* __restrict__ Cadj,
            const float* __restrict__ S, const u16* __restrict__ G,
            const u16* __restrict__ PB, void* __restrict__ out,
            const void* __restrict__ rawIn)
{
  __shared__ __align__(16) u16 ldsA[32 * 64];    // 4 KB
  __shared__ __align__(16) u16 ldsB[256 * 64];   // 32 KB
  __shared__ float red[32][4];
  const int et = blockIdx.x, b = blockIdx.y;
  const int e0 = et << 5;
  const int tid = threadIdx.x, wave = tid >> 6, lane = tid & 63;
  const int wm = wave >> 1, wn = wave & 1;
  const size_t abase = ((size_t)((b << 9) + e0)) << 9;
  const u16* Ea  = E + abase;
  const u16* Aa  = Cadj + abase;
  const u16* Tb  = T + ((size_t)b << 18);
  const u16* WhvT = Tb + (256 << 9);
  const u16* SupT = Tb;
  const u16* dgf_b = PB + 32768;
  const u16* ln_g  = PB + 33536;
  const u16* ln_b  = PB + 33792;
  const u32 isf32 = detectf32(rawIn);

  f32x4 acc[2][8];
#pragma unroll
  for (int p = 0; p < 2; ++p)
#pragma unroll
    for (int j = 0; j < 8; ++j) acc[p][j] = f32x4{0.f, 0.f, 0.f, 0.f};

#pragma unroll
  for (int ph = 0; ph < 2; ++ph) {
    const u16* Ag = ph ? Aa : Ea;
    const u16* Bg = ph ? SupT : WhvT;
    for (int lt = 0; lt < 8; ++lt) {
      __syncthreads();
      {
        const int slot = (wave << 6) + lane;
        const int m = slot >> 3, c = slot & 7;
        const int kb = c ^ (m & 7);
        *(uint4*)&ldsA[slot << 3] =
            *(const uint4*)(Ag + (m << 9) + (lt << 6) + (kb << 3));
      }
#pragma unroll
      for (int s2 = 0; s2 < 8; ++s2) {
        const int slot = ((wave * 8 + s2) << 6) + lane;
        const int m = slot >> 3, c = slot & 7;
        const int kb = c ^ (m & 7);
        *(uint4*)&ldsB[slot << 3] =
            *(const uint4*)(Bg + (m << 9) + (lt << 6) + (kb << 3));
      }
      __syncthreads();
#pragma unroll
      for (int ks = 0; ks < 2; ++ks) {
        const int kb = (ks << 2) + (lane >> 4);
        const int m = (wm << 4) + (lane & 15);
        const bf16x8 fa = *(const bf16x8*)&ldsA[((m << 3) + (kb ^ (m & 7))) << 3];
#pragma unroll
        for (int j = 0; j < 8; ++j) {
          const int n = (wn << 7) + (j << 4) + (lane & 15);
          const bf16x8 fb = *(const bf16x8*)&ldsB[((n << 3) + (kb ^ (n & 7))) << 3];
          acc[ph][j] = MFMA16(fa, fb, acc[ph][j]);
        }
      }
    }
  }

  const int cb = wn << 7;
  float lng[8], lnb[8], dgb[8];
#pragma unroll
  for (int j = 0; j < 8; ++j) {
    const int col = cb + (j << 4) + (lane & 15);
    lng[j] = bf2f(ln_g[col]);
    lnb[j] = bf2f(ln_b[col]);
    dgb[j] = bf2f(dgf_b[col]);
  }
#pragma unroll
  for (int r = 0; r < 4; ++r) {
    const int rl = (wm << 4) + ((lane >> 4) << 2) + r;
    const int grow = (b << 9) + e0 + rl;
    const float invS = 1.0f / S[grow];
    float ps = 0.0f, pq = 0.0f;
#pragma unroll
    for (int j = 0; j < 8; ++j) {
      const int col = cb + (j << 4) + (lane & 15);
      const float gg = bf2f(G[((size_t)grow << 9) + 256 + col]);
      const float hp = gg * acc[0][j][r] * invS;
      acc[0][j][r] = hp;
      ps += hp; pq += hp * hp;
    }
#pragma unroll
    for (int m = 1; m < 16; m <<= 1) {
      ps += __shfl_xor(ps, m, 64);
      pq += __shfl_xor(pq, m, 64);
    }
    if ((lane & 15) == 0) { red[rl][wn << 1] = ps; red[rl][(wn << 1) + 1] = pq; }
  }
  __syncthreads();
#pragma unroll
  for (int r = 0; r < 4; ++r) {
    const int rl = (wm << 4) + ((lane >> 4) << 2) + r;
    const int grow = (b << 9) + e0 + rl;
    const float mean = (red[rl][0] + red[rl][2]) * (1.0f / 256.0f);
    const float ex2  = (red[rl][1] + red[rl][3]) * (1.0f / 256.0f);
    const float rstd = rsqrtf(ex2 - mean * mean + 1e-5f);
#pragma unroll
    for (int j = 0; j < 8; ++j) {
      const int col = cb + (j << 4) + (lane & 15);
      const float gat = (acc[0][j][r] - mean) * rstd * lng[j] + lnb[j];
      const float gd = bf2f(G[((size_t)grow << 9) + col]);
      const float sup = bf2f(P[grow * 768 + col]);
      const float dense = gd * acc[1][j][r] + sup + dgb[j];
      const float o = 0.5f * (dense + gat);
      if (isf32) ((float*)out)[grow * 256 + col] = o;
      else       ((u16*)out)[grow * 256 + col] = f2bf(o);
    }
  }
}

// ---------------------------------------------------------------------------
extern "C" void kernel_launch(void* const* d_in, const int* in_sizes, int n_in,
                              void* d_out, int out_size, void* d_ws, size_t ws_size,
                              hipStream_t stream)
{
  (void)in_sizes; (void)n_in; (void)out_size; (void)ws_size;
  const void* inputs  = d_in[0];
  const void* adj     = d_in[1];
  const void* op_emb  = d_in[2];
  const void* dgf_W   = d_in[3];
  const void* dgf_b   = d_in[4];
  const void* dgf_opW = d_in[5];
  const void* dgf_opb = d_in[6];
  const void* Wk      = d_in[7];
  const void* Wv      = d_in[8];
  const void* Wq      = d_in[9];
  const void* a_w     = d_in[10];
  const void* gat_opW = d_in[11];
  const void* gat_opb = d_in[12];
  const void* ln_g    = d_in[13];
  const void* ln_b    = d_in[14];
  char* ws = (char*)d_ws;

  // workspace layout (bytes)
  u16*  P    = (u16*)(ws);                    // [32768,768]  50331648
  u16*  T    = (u16*)(ws + 50331648ull);      // [64,512,512] 33554432
  u16*  E    = (u16*)(ws + 83886080ull);      // [64,512,512] 33554432
  u16*  G    = (u16*)(ws + 117440512ull);     // [32768,512]  33554432
  u16*  Cadj = (u16*)(ws + 150994944ull);     // [64,512,512] 33554432
  u16*  Cin  = (u16*)(ws + 184549376ull);     // [32768,256]  16777216
  u16*  Cop  = (u16*)(ws + 201326592ull);     // [32768,64]    4194304
  u16*  Wcat = (u16*)(ws + 205520896ull);     // [1024,256]     524288
  u16*  PB   = (u16*)(ws + 206045184ull);     // params          69632
  float* Srw = (float*)(ws + 206114816ull);   // [32768] f32    131072

  kPrep    <<<dim3(6310),     dim3(256), 0, stream>>>(inputs, op_emb,
                dgf_W, Wk, Wv, Wq, a_w, dgf_opW, gat_opW, dgf_b, dgf_opb,
                gat_opb, ln_g, ln_b, Cin, Cop, Wcat, PB, Srw);
  k1_proj  <<<dim3(256, 10),  dim3(256), 0, stream>>>(Cin, Wcat, P, T);
  k2_gates <<<dim3(256, 4),   dim3(256), 0, stream>>>(Cop, PB, G);
  k3_scores<<<dim3(4, 4, 64), dim3(256), 0, stream>>>(P, adj, E, Cadj, Srw);
  k4_out   <<<dim3(16, 64),   dim3(256), 0, stream>>>(P, T, E, Cadj, Srw, G,
                                                      PB, d_out, inputs);
}

// Round 7
// 372.607 us; speedup vs baseline: 1.3554x; 1.1174x over previous
//
#include <hip/hip_runtime.h>
#include <cstdint>
#include <cstddef>

typedef unsigned short u16;
typedef unsigned int   u32;
typedef __attribute__((ext_vector_type(8))) short bf16x8;
typedef __attribute__((ext_vector_type(4))) float f32x4;

#define MFMA16(a,b,c) __builtin_amdgcn_mfma_f32_16x16x32_bf16((a),(b),(c),0,0,0)

__device__ __forceinline__ float bf2f(u16 h){
  union { u32 u; float f; } v; v.u = ((u32)h) << 16; return v.f;
}
__device__ __forceinline__ u16 f2bf(float f){
  union { float f; u32 u; } v; v.f = f;
  u32 u = v.u + 0x7FFFu + ((v.u >> 16) & 1u);
  return (u16)(u >> 16);
}
__device__ __forceinline__ float ldf(const void* p, int i, u32 isf32){
  return isf32 ? ((const float*)p)[i] : bf2f(((const u16*)p)[i]);
}
// inline dtype probe: raw f32 data seen as bf16 has huge low-half values
__device__ __forceinline__ u32 detectf32(const void* p){
  const float v = bf2f(((const u16*)p)[threadIdx.x & 63]);
  return (__ballot(fabsf(v) > 1.0e6f) != 0ull) ? 1u : 0u;
}
__device__ __forceinline__ void conv8(const void* src, u16* dst, int i8, u32 f){
  if (f) {
    const float4 a = ((const float4*)src)[i8 >> 2];
    const float4 b = ((const float4*)src)[(i8 >> 2) + 1];
    u16 o[8] = { f2bf(a.x), f2bf(a.y), f2bf(a.z), f2bf(a.w),
                 f2bf(b.x), f2bf(b.y), f2bf(b.z), f2bf(b.w) };
    *(uint4*)&dst[i8] = *(const uint4*)o;
  } else {
    ((uint4*)dst)[i8 >> 3] = ((const uint4*)src)[i8 >> 3];
  }
}

// ---------------------------------------------------------------------------
// kPrep: fused conversion/param staging (see R5 comments for PB map).
// ---------------------------------------------------------------------------
__global__ void kPrep(const void* inputs, const void* op_emb,
                      const void* dgfW, const void* Wk, const void* Wv,
                      const void* Wq, const void* aw,
                      const void* dgf_opW, const void* gat_opW,
                      const void* dgf_b, const void* dgf_opb,
                      const void* gat_opb, const void* ln_g, const void* ln_b,
                      u16* __restrict__ Cin, u16* __restrict__ Cop,
                      u16* __restrict__ Wcat, u16* __restrict__ PB,
                      float* __restrict__ Srw)
{
  const u32 f = detectf32(inputs);
  const int bid = blockIdx.x, tid = threadIdx.x;
  if (bid < 4096) {
    conv8(inputs, Cin, ((bid << 8) + tid) << 3, f);
  } else if (bid < 5120) {
    conv8(op_emb, Cop, (((bid - 4096) << 8) + tid) << 3, f);
  } else if (bid < 6144) {
    const int o = bid - 5120, i = tid;
    float v;
    if (o < 256)       v = ldf(dgfW, i * 256 + o, f);
    else if (o < 512)  v = ldf(Wk, (o - 256) * 256 + i, f);
    else if (o < 768)  v = ldf(Wv, (o - 512) * 256 + i, f);
    else               v = ldf(Wq, (o - 768) * 256 + i, f) * ldf(aw, o - 768, f) * 0.0625f;
    Wcat[o * 256 + i] = f2bf(v);
  } else if (bid < 6278) {
    const int i = ((bid - 6144) << 8) + tid;
    if (i < 34048) {
      float v;
      if      (i < 16384) v = ldf(dgf_opW, i, f);
      else if (i < 32768) v = ldf(gat_opW, i - 16384, f);
      else if (i < 33024) v = ldf(dgf_b,   i - 32768, f);
      else if (i < 33280) v = ldf(dgf_opb, i - 33024, f);
      else if (i < 33536) v = ldf(gat_opb, i - 33280, f);
      else if (i < 33792) v = ldf(ln_g,    i - 33536, f);
      else                v = ldf(ln_b,    i - 33792, f);
      PB[i] = f2bf(v);
    }
  } else {
    ((float4*)Srw)[((bid - 6278) << 8) + tid] = float4{0.f, 0.f, 0.f, 0.f};
  }
}

// ---------------------------------------------------------------------------
// K1: A-resident projection. One block per 128-row X tile; X tile (128x256,
// 64 KB) staged ONCE into LDS, then loop over 10 col-tiles of Wcat staging
// only the 16 KB W-tile per kt. Cuts X traffic 10x.
// A LDS layout: chunk(m, kt, cpos) at (m*32 + kt*8 + cpos)*8 elements,
// content X[m][kt*64 + (cpos^(m&7))*8]  (XOR swizzle within kt-group).
// ct 0-3: support/Whk -> P ; 6,7: Whq_pre -> P
// ct 4,5: Whv -> T rows 256-511 (swapped => C^T) ; 8,9: support -> T rows 0-255
// ---------------------------------------------------------------------------
__global__ __launch_bounds__(256, 1)
void k1_proj(const u16* __restrict__ X, const u16* __restrict__ W,
             u16* __restrict__ P, u16* __restrict__ T)
{
  __shared__ __align__(16) u16 ldsA[128 * 256];   // 64 KB, resident X tile
  __shared__ __align__(16) u16 ldsB[128 * 64];    // 16 KB, W tile per kt
  const int bt = blockIdx.x;
  const int r0 = bt << 7;
  const int tid = threadIdx.x;
  const int wave = tid >> 6;
  const int lane = tid & 63;
  const int wm = wave >> 1, wn = wave & 1;

  // stage full A tile (4096 chunks of 16B)
#pragma unroll
  for (int it = 0; it < 16; ++it) {
    const int slot = (it << 8) + tid;
    const int m = slot >> 5, c = slot & 31;
    const int kt = c >> 3, cpos = c & 7;
    const int col = (kt << 6) + ((cpos ^ (m & 7)) << 3);
    *(uint4*)&ldsA[slot << 3] = *(const uint4*)(X + (r0 + m) * 256 + col);
  }
  __syncthreads();

  for (int ct = 0; ct < 10; ++ct) {
    const bool swapped = (ct == 4) | (ct == 5) | (ct >= 8);
    const int wbase = (ct < 8) ? (ct << 7) : ((ct - 8) << 7);

    f32x4 acc[4][4];
#pragma unroll
    for (int i = 0; i < 4; ++i)
#pragma unroll
      for (int j = 0; j < 4; ++j) acc[i][j] = f32x4{0.f, 0.f, 0.f, 0.f};

    for (int kt = 0; kt < 4; ++kt) {
      __syncthreads();
#pragma unroll
      for (int s = 0; s < 4; ++s) {
        const int slot = ((wave * 4 + s) << 6) + lane;
        const int m = slot >> 3, c = slot & 7;
        const int kb = c ^ (m & 7);
        *(uint4*)&ldsB[slot << 3] =
            *(const uint4*)(W + (wbase + m) * 256 + (kt << 6) + (kb << 3));
      }
      __syncthreads();
#pragma unroll
      for (int ks = 0; ks < 2; ++ks) {
        const int kb = (ks << 2) + (lane >> 4);
        bf16x8 fa[4], fb[4];
#pragma unroll
        for (int i = 0; i < 4; ++i) {
          const int m = (wm << 6) + (i << 4) + (lane & 15);
          fa[i] = *(const bf16x8*)&ldsA[((m << 5) + (kt << 3) + (kb ^ (m & 7))) << 3];
          const int n = (wn << 6) + (i << 4) + (lane & 15);
          fb[i] = *(const bf16x8*)&ldsB[((n << 3) + (kb ^ (n & 7))) << 3];
        }
        if (!swapped) {
#pragma unroll
          for (int i = 0; i < 4; ++i)
#pragma unroll
            for (int j = 0; j < 4; ++j)
              acc[i][j] = MFMA16(fa[i], fb[j], acc[i][j]);
        } else {
#pragma unroll
          for (int i = 0; i < 4; ++i)
#pragma unroll
            for (int j = 0; j < 4; ++j)
              acc[i][j] = MFMA16(fb[i], fa[j], acc[i][j]);
        }
      }
    }

    if (!swapped) {
      const int pcb = (ct < 4) ? (ct << 7) : ((ct - 2) << 7);
#pragma unroll
      for (int i = 0; i < 4; ++i) {
        const int row = r0 + (wm << 6) + (i << 4) + ((lane >> 4) << 2);
#pragma unroll
        for (int j = 0; j < 4; ++j) {
          const int col = pcb + (wn << 6) + (j << 4) + (lane & 15);
#pragma unroll
          for (int r = 0; r < 4; ++r)
            P[(row + r) * 768 + col] = f2bf(acc[i][j][r]);
        }
      }
    } else {
      // swapped: C rows carry wn offset, C cols carry wm offset
      const int trb = (wbase >= 512) ? (wbase - 256) : wbase;
      const int b = r0 >> 9;
      const int e0 = r0 & 511;
      u16* Tb = T + ((size_t)b << 18);
#pragma unroll
      for (int i = 0; i < 4; ++i) {
        const int trow = trb + (wn << 6) + (i << 4) + ((lane >> 4) << 2);
#pragma unroll
        for (int j = 0; j < 4; ++j) {
          const int e = e0 + (wm << 6) + (j << 4) + (lane & 15);
#pragma unroll
          for (int r = 0; r < 4; ++r)
            Tb[((trow + r) << 9) + e] = f2bf(acc[i][j][r]);
        }
      }
    }
  }
}

// ---------------------------------------------------------------------------
// K2: G[32768,512] = sigmoid(op_emb @ opW^T + b); cols 0-255 gate_d, 256-511 gate_g
// ---------------------------------------------------------------------------
__global__ __launch_bounds__(256, 2)
void k2_gates(const u16* __restrict__ OP, const u16* __restrict__ PB,
              u16* __restrict__ G)
{
  __shared__ __align__(16) u16 ldsA[128 * 64];
  __shared__ __align__(16) u16 ldsB[128 * 64];
  const int bt = blockIdx.x, ct = blockIdx.y;
  const int r0 = bt << 7;
  const u16* Wp = (ct < 2) ? (PB + (ct << 7) * 64) : (PB + 16384 + ((ct - 2) << 7) * 64);
  const u16* Bp = (ct < 2) ? (PB + 33024 + (ct << 7)) : (PB + 33280 + ((ct - 2) << 7));
  const int tid = threadIdx.x, wave = tid >> 6, lane = tid & 63;
  const int wm = wave >> 1, wn = wave & 1;

  f32x4 acc[4][4];
#pragma unroll
  for (int i = 0; i < 4; ++i)
#pragma unroll
    for (int j = 0; j < 4; ++j) acc[i][j] = f32x4{0.f, 0.f, 0.f, 0.f};

#pragma unroll
  for (int s = 0; s < 4; ++s) {
    const int slot = ((wave * 4 + s) << 6) + lane;
    const int m = slot >> 3, c = slot & 7;
    const int kb = c ^ (m & 7);
    *(uint4*)&ldsA[slot << 3] = *(const uint4*)(OP + (r0 + m) * 64 + (kb << 3));
    *(uint4*)&ldsB[slot << 3] = *(const uint4*)(Wp + m * 64 + (kb << 3));
  }
  __syncthreads();
#pragma unroll
  for (int ks = 0; ks < 2; ++ks) {
    const int kb = (ks << 2) + (lane >> 4);
    bf16x8 fa[4], fb[4];
#pragma unroll
    for (int i = 0; i < 4; ++i) {
      const int m = (wm << 6) + (i << 4) + (lane & 15);
      fa[i] = *(const bf16x8*)&ldsA[((m << 3) + (kb ^ (m & 7))) << 3];
      const int n = (wn << 6) + (i << 4) + (lane & 15);
      fb[i] = *(const bf16x8*)&ldsB[((n << 3) + (kb ^ (n & 7))) << 3];
    }
#pragma unroll
    for (int i = 0; i < 4; ++i)
#pragma unroll
      for (int j = 0; j < 4; ++j)
        acc[i][j] = MFMA16(fa[i], fb[j], acc[i][j]);
  }
#pragma unroll
  for (int i = 0; i < 4; ++i) {
    const int row = r0 + (wm << 6) + (i << 4) + ((lane >> 4) << 2);
#pragma unroll
    for (int j = 0; j < 4; ++j) {
      const int cw = (wn << 6) + (j << 4) + (lane & 15);
      const float bias = bf2f(Bp[cw]);
      const int col = (ct << 7) + cw;
#pragma unroll
      for (int r = 0; r < 4; ++r) {
        const float x = acc[i][j][r] + bias;
        G[((row + r) << 9) + col] = f2bf(1.0f / (1.0f + __expf(-x)));
      }
    }
  }
}

// ---------------------------------------------------------------------------
// K3: scores S = Whq_pre @ Whk^T. Epilogue: reads RAW adj (dtype branch),
// writes E = exp(leaky(S)*adj) bf16, Cadj = bf16(adj), atomicAdds row sums.
// Grid (64,16): x=b so a batch's 16 tiles share one XCD's L2.
// ---------------------------------------------------------------------------
__global__ __launch_bounds__(256, 2)
void k3_scores(const u16* __restrict__ P, const void* __restrict__ adjR,
               u16* __restrict__ E, u16* __restrict__ Cadj,
               float* __restrict__ Srw)
{
  __shared__ __align__(16) u16 ldsA[128 * 64];
  __shared__ __align__(16) u16 ldsB[128 * 64];
  const int b = blockIdx.x;
  const int lt = blockIdx.y & 3, et = blockIdx.y >> 2;
  const int e0 = et << 7, l0 = lt << 7;
  const int tid = threadIdx.x, wave = tid >> 6, lane = tid & 63;
  const int wm = wave >> 1, wn = wave & 1;
  const int rowQ = (b << 9) + e0;
  const int rowK = (b << 9) + l0;
  const u32 isf32 = detectf32(adjR);

  f32x4 acc[4][4];
#pragma unroll
  for (int i = 0; i < 4; ++i)
#pragma unroll
    for (int j = 0; j < 4; ++j) acc[i][j] = f32x4{0.f, 0.f, 0.f, 0.f};

  for (int kt = 0; kt < 4; ++kt) {
    __syncthreads();
#pragma unroll
    for (int s = 0; s < 4; ++s) {
      const int slot = ((wave * 4 + s) << 6) + lane;
      const int m = slot >> 3, c = slot & 7;
      const int kb = c ^ (m & 7);
      *(uint4*)&ldsA[slot << 3] =
          *(const uint4*)(P + (rowQ + m) * 768 + 512 + (kt << 6) + (kb << 3));
      *(uint4*)&ldsB[slot << 3] =
          *(const uint4*)(P + (rowK + m) * 768 + 256 + (kt << 6) + (kb << 3));
    }
    __syncthreads();
#pragma unroll
    for (int ks = 0; ks < 2; ++ks) {
      const int kb = (ks << 2) + (lane >> 4);
      bf16x8 fa[4], fb[4];
#pragma unroll
      for (int i = 0; i < 4; ++i) {
        const int m = (wm << 6) + (i << 4) + (lane & 15);
        fa[i] = *(const bf16x8*)&ldsA[((m << 3) + (kb ^ (m & 7))) << 3];
        const int n = (wn << 6) + (i << 4) + (lane & 15);
        fb[i] = *(const bf16x8*)&ldsB[((n << 3) + (kb ^ (n & 7))) << 3];
      }
#pragma unroll
      for (int i = 0; i < 4; ++i)
#pragma unroll
        for (int j = 0; j < 4; ++j)
          acc[i][j] = MFMA16(fa[i], fb[j], acc[i][j]);
    }
  }
#pragma unroll
  for (int i = 0; i < 4; ++i) {
#pragma unroll
    for (int r = 0; r < 4; ++r) {
      const int e = e0 + (wm << 6) + (i << 4) + ((lane >> 4) << 2) + r;
      const int grow = (b << 9) + e;
      float part = 0.0f;
#pragma unroll
      for (int j = 0; j < 4; ++j) {
        const int l = l0 + (wn << 6) + (j << 4) + (lane & 15);
        const int idx = (grow << 9) + l;
        const float a = isf32 ? ((const float*)adjR)[idx]
                              : bf2f(((const u16*)adjR)[idx]);
        float s = acc[i][j][r];
        s = (s > 0.0f ? s : 0.2f * s) * a;
        const float ex = __expf(s);
        E[idx] = f2bf(ex);
        Cadj[idx] = f2bf(a);
        part += ex;
      }
#pragma unroll
      for (int m = 1; m < 16; m <<= 1) part += __shfl_xor(part, m, 64);
      if ((lane & 15) == 0) atomicAdd(&Srw[grow], part);
    }
  }
}

// ---------------------------------------------------------------------------
// K4 (R4-proven 64-row config): per (b, 64-row e-tile):
// phase0 H = E @ Whv (via WhvT); phase1 D = adj @ support (via supportT).
// Epilogue: h'=gate_g*H/S; LayerNorm; dense=gate_d*D+support+dgf_b;
// out=0.5*(dense+gat). Grid (64,8): x=b for XCD locality of T/E/Cadj.
// ---------------------------------------------------------------------------
__global__ __launch_bounds__(256, 2)
void k4_out(const u16* __restrict__ P, const u16* __restrict__ T,
            const u16* __restrict__ E, const u16* __restrict__ Cadj,
            const float* __restrict__ S, const u16* __restrict__ G,
            const u16* __restrict__ PB, void* __restrict__ out,
            const void* __restrict__ rawIn)
{
  __shared__ __align__(16) u16 ldsA[64 * 64];
  __shared__ __align__(16) u16 ldsB[256 * 64];
  __shared__ float red[64][4];
  const int b = blockIdx.x, et = blockIdx.y;
  const int e0 = et << 6;
  const int tid = threadIdx.x, wave = tid >> 6, lane = tid & 63;
  const int wm = wave >> 1, wn = wave & 1;
  const size_t abase = ((size_t)((b << 9) + e0)) << 9;
  const u16* Ea  = E + abase;
  const u16* Aa  = Cadj + abase;
  const u16* Tb  = T + ((size_t)b << 18);
  const u16* WhvT = Tb + (256 << 9);
  const u16* SupT = Tb;
  const u16* dgf_b = PB + 32768;
  const u16* ln_g  = PB + 33536;
  const u16* ln_b  = PB + 33792;
  const u32 isf32 = detectf32(rawIn);

  f32x4 acc[2][2][8];
#pragma unroll
  for (int p = 0; p < 2; ++p)
#pragma unroll
    for (int i = 0; i < 2; ++i)
#pragma unroll
      for (int j = 0; j < 8; ++j) acc[p][i][j] = f32x4{0.f, 0.f, 0.f, 0.f};

#pragma unroll
  for (int ph = 0; ph < 2; ++ph) {
    const u16* Ag = ph ? Aa : Ea;
    const u16* Bg = ph ? SupT : WhvT;
    for (int lt = 0; lt < 8; ++lt) {
      __syncthreads();
#pragma unroll
      for (int s2 = 0; s2 < 2; ++s2) {
        const int slot = ((wave * 2 + s2) << 6) + lane;
        const int m = slot >> 3, c = slot & 7;
        const int kb = c ^ (m & 7);
        *(uint4*)&ldsA[slot << 3] =
            *(const uint4*)(Ag + (m << 9) + (lt << 6) + (kb << 3));
      }
#pragma unroll
      for (int s2 = 0; s2 < 8; ++s2) {
        const int slot = ((wave * 8 + s2) << 6) + lane;
        const int m = slot >> 3, c = slot & 7;
        const int kb = c ^ (m & 7);
        *(uint4*)&ldsB[slot << 3] =
            *(const uint4*)(Bg + (m << 9) + (lt << 6) + (kb << 3));
      }
      __syncthreads();
#pragma unroll
      for (int ks = 0; ks < 2; ++ks) {
        const int kb = (ks << 2) + (lane >> 4);
        bf16x8 fa[2];
#pragma unroll
        for (int i = 0; i < 2; ++i) {
          const int m = (wm << 5) + (i << 4) + (lane & 15);
          fa[i] = *(const bf16x8*)&ldsA[((m << 3) + (kb ^ (m & 7))) << 3];
        }
#pragma unroll
        for (int j = 0; j < 8; ++j) {
          const int n = (wn << 7) + (j << 4) + (lane & 15);
          const bf16x8 fb = *(const bf16x8*)&ldsB[((n << 3) + (kb ^ (n & 7))) << 3];
          acc[ph][0][j] = MFMA16(fa[0], fb, acc[ph][0][j]);
          acc[ph][1][j] = MFMA16(fa[1], fb, acc[ph][1][j]);
        }
      }
    }
  }

  const int cb = wn << 7;
  float lng[8], lnb[8], dgb[8];
#pragma unroll
  for (int j = 0; j < 8; ++j) {
    const int col = cb + (j << 4) + (lane & 15);
    lng[j] = bf2f(ln_g[col]);
    lnb[j] = bf2f(ln_b[col]);
    dgb[j] = bf2f(dgf_b[col]);
  }
#pragma unroll
  for (int i = 0; i < 2; ++i) {
#pragma unroll
    for (int r = 0; r < 4; ++r) {
      const int rl = (wm << 5) + (i << 4) + ((lane >> 4) << 2) + r;
      const int grow = (b << 9) + e0 + rl;
      const float invS = 1.0f / S[grow];
      float ps = 0.0f, pq = 0.0f;
#pragma unroll
      for (int j = 0; j < 8; ++j) {
        const int col = cb + (j << 4) + (lane & 15);
        const float gg = bf2f(G[((size_t)grow << 9) + 256 + col]);
        const float hp = gg * acc[0][i][j][r] * invS;
        acc[0][i][j][r] = hp;
        ps += hp; pq += hp * hp;
      }
#pragma unroll
      for (int m = 1; m < 16; m <<= 1) {
        ps += __shfl_xor(ps, m, 64);
        pq += __shfl_xor(pq, m, 64);
      }
      if ((lane & 15) == 0) { red[rl][wn << 1] = ps; red[rl][(wn << 1) + 1] = pq; }
    }
  }
  __syncthreads();
#pragma unroll
  for (int i = 0; i < 2; ++i) {
#pragma unroll
    for (int r = 0; r < 4; ++r) {
      const int rl = (wm << 5) + (i << 4) + ((lane >> 4) << 2) + r;
      const int grow = (b << 9) + e0 + rl;
      const float mean = (red[rl][0] + red[rl][2]) * (1.0f / 256.0f);
      const float ex2  = (red[rl][1] + red[rl][3]) * (1.0f / 256.0f);
      const float rstd = rsqrtf(ex2 - mean * mean + 1e-5f);
#pragma unroll
      for (int j = 0; j < 8; ++j) {
        const int col = cb + (j << 4) + (lane & 15);
        const float gat = (acc[0][i][j][r] - mean) * rstd * lng[j] + lnb[j];
        const float gd = bf2f(G[((size_t)grow << 9) + col]);
        const float sup = bf2f(P[grow * 768 + col]);
        const float dense = gd * acc[1][i][j][r] + sup + dgb[j];
        const float o = 0.5f * (dense + gat);
        if (isf32) ((float*)out)[grow * 256 + col] = o;
        else       ((u16*)out)[grow * 256 + col] = f2bf(o);
      }
    }
  }
}

// ---------------------------------------------------------------------------
extern "C" void kernel_launch(void* const* d_in, const int* in_sizes, int n_in,
                              void* d_out, int out_size, void* d_ws, size_t ws_size,
                              hipStream_t stream)
{
  (void)in_sizes; (void)n_in; (void)out_size; (void)ws_size;
  const void* inputs  = d_in[0];
  const void* adj     = d_in[1];
  const void* op_emb  = d_in[2];
  const void* dgf_W   = d_in[3];
  const void* dgf_b   = d_in[4];
  const void* dgf_opW = d_in[5];
  const void* dgf_opb = d_in[6];
  const void* Wk      = d_in[7];
  const void* Wv      = d_in[8];
  const void* Wq      = d_in[9];
  const void* a_w     = d_in[10];
  const void* gat_opW = d_in[11];
  const void* gat_opb = d_in[12];
  const void* ln_g    = d_in[13];
  const void* ln_b    = d_in[14];
  char* ws = (char*)d_ws;

  // workspace layout (bytes)
  u16*  P    = (u16*)(ws);                    // [32768,768]  50331648
  u16*  T    = (u16*)(ws + 50331648ull);      // [64,512,512] 33554432
  u16*  E    = (u16*)(ws + 83886080ull);      // [64,512,512] 33554432
  u16*  G    = (u16*)(ws + 117440512ull);     // [32768,512]  33554432
  u16*  Cadj = (u16*)(ws + 150994944ull);     // [64,512,512] 33554432
  u16*  Cin  = (u16*)(ws + 184549376ull);     // [32768,256]  16777216
  u16*  Cop  = (u16*)(ws + 201326592ull);     // [32768,64]    4194304
  u16*  Wcat = (u16*)(ws + 205520896ull);     // [1024,256]     524288
  u16*  PB   = (u16*)(ws + 206045184ull);     // params          69632
  float* Srw = (float*)(ws + 206114816ull);   // [32768] f32    131072

  kPrep    <<<dim3(6310),    dim3(256), 0, stream>>>(inputs, op_emb,
                dgf_W, Wk, Wv, Wq, a_w, dgf_opW, gat_opW, dgf_b, dgf_opb,
                gat_opb, ln_g, ln_b, Cin, Cop, Wcat, PB, Srw);
  k1_proj  <<<dim3(256),     dim3(256), 0, stream>>>(Cin, Wcat, P, T);
  k2_gates <<<dim3(256, 4),  dim3(256), 0, stream>>>(Cop, PB, G);
  k3_scores<<<dim3(64, 16),  dim3(256), 0, stream>>>(P, adj, E, Cadj, Srw);
  k4_out   <<<dim3(64, 8),   dim3(256), 0, stream>>>(P, T, E, Cadj, Srw, G,
                                                     PB, d_out, inputs);
}